// Round 6
// baseline (232.463 us; speedup 1.0000x reference)
//
#include <hip/hip_runtime.h>

#define D 64
#define TILE 128
#define W 16            // B-tiles per block (chunk length)

typedef __attribute__((ext_vector_type(8))) short short8;
typedef __attribute__((ext_vector_type(4))) float f32x4;
typedef __attribute__((ext_vector_type(8))) unsigned short ushort8;

#define CC     (-0.7213475204444817f)   // -log2(e)/(2*sigma^2), sigma=1
#define SCALE  (1.2011224087864498f)    // sqrt(2*log2(e)); dot(scaled) = -2C*dot
#define THR    (-28.0f)                 // drop terms < 2^-28: total mass < 3 -> <3e-8 on output

// ---------------------------------------------------------------------------
// Prep: fp32 -> bf16 (RNE), PRE-SCALED by sqrt(2*log2 e), LINEAR row layout
// (no LDS anywhere downstream -> no swizzle; keeps B-frag loads coalesced).
// Norms stored PRE-MULTIPLIED by C. Padded rows: zeros + C*1e30.
// ---------------------------------------------------------------------------
__global__ void prep_kernel(const float* __restrict__ X, const float* __restrict__ Y,
                            unsigned short* __restrict__ Xbf, unsigned short* __restrict__ Ybf,
                            float* __restrict__ nx, float* __restrict__ ny,
                            int nX, int nY, int padN) {
    int t = blockIdx.x * blockDim.x + threadIdx.x;
    int half = padN * 8;
    if (t >= 2 * half) return;

    const float* src; unsigned short* dst; float* nrm; int n; int tt;
    if (t < half) { src = X; dst = Xbf; nrm = nx; n = nX; tt = t; }
    else          { src = Y; dst = Ybf; nrm = ny; n = nY; tt = t - half; }

    int row = tt >> 3, c8 = tt & 7;

    float v[8];
    float ss = 0.f;
    if (row < n) {
        const float4* p = (const float4*)(src + (size_t)row * D + c8 * 8);
        float4 f0 = p[0], f1 = p[1];
        v[0] = f0.x; v[1] = f0.y; v[2] = f0.z; v[3] = f0.w;
        v[4] = f1.x; v[5] = f1.y; v[6] = f1.z; v[7] = f1.w;
#pragma unroll
        for (int i = 0; i < 8; ++i) ss += v[i] * v[i];
    } else {
#pragma unroll
        for (int i = 0; i < 8; ++i) v[i] = 0.f;
    }

    ss += __shfl_xor(ss, 1, 64);
    ss += __shfl_xor(ss, 2, 64);
    ss += __shfl_xor(ss, 4, 64);

    ushort8 o;
#pragma unroll
    for (int i = 0; i < 8; ++i) {
        unsigned u = __float_as_uint(v[i] * SCALE);
        o[i] = (unsigned short)((u + 0x7fffu + ((u >> 16) & 1u)) >> 16);   // RNE
    }
    *(ushort8*)(dst + (size_t)row * D + c8 * 8) = o;

    if (c8 == 0) nrm[row] = (row < n) ? (CC * ss) : (CC * 1e30f);
}

// ---------------------------------------------------------------------------
// Barrier-free persistent-A gram kernel. NO LDS. Each wave owns a 64x64
// sub-tile of the block's 128x128 x W chunk: A-frags + A-norms (u4 = MFMA
// C-in) in registers for the whole block; B-frags + B-norms read directly
// from global (L1/L2-hot), one tile ahead, unroll-2 ping-pong (named register
// sets -> all static indexing). Waves run fully independent; per-wave partial
// written to global. Fast path: bound = max(acc)+max(v) vs THR (max3 tree).
// z=0: xx (bj>=bi, x2 off-diag), z=1: yy, z=2: xy (full rows).
// ---------------------------------------------------------------------------
__launch_bounds__(256, 2)
__global__ void gram_kernel(const unsigned short* __restrict__ Xbf,
                            const unsigned short* __restrict__ Ybf,
                            const float* __restrict__ nx, const float* __restrict__ ny,
                            int nX, int nY, int NT, int CH, float* __restrict__ part) {
    const int c   = blockIdx.x;
    const int bi  = blockIdx.y;
    const int z   = blockIdx.z;
    const int tid = threadIdx.x;
    const int w = tid >> 6, lane = tid & 63;
    const int lin4 = ((z * NT + bi) * CH + c) * 4 + w;

    const int bj0 = (z < 2 ? bi : 0) + c * W;
    int ntiles = NT - bj0; if (ntiles > W) ntiles = W;
    if (ntiles <= 0) { if (lane == 0) part[lin4] = 0.f; return; }

    const unsigned short* Abase; const unsigned short* Bbase;
    const float* nA; const float* nB; int rA;
    if (z == 0)      { Abase = Xbf; Bbase = Xbf; nA = nx; nB = nx; rA = nX; }
    else if (z == 1) { Abase = Ybf; Bbase = Ybf; nA = ny; nB = ny; rA = nY; }
    else             { Abase = Xbf; Bbase = Ybf; nA = nx; nB = ny; rA = nX; }

    const int a0 = bi * TILE;
    const int wm = (w & 1) * 64, wn = (w >> 1) * 64;
    const int lhi = lane >> 4, llo = lane & 15;

    // ---- A-panel fragments + A-norms, registers for the whole block ----
    const unsigned short* Ap = Abase + ((size_t)(a0 + wm) + llo) * D + lhi * 8;
    short8 af0[4], af1[4];
#pragma unroll
    for (int fm = 0; fm < 4; ++fm) {
        af0[fm] = *(const short8*)&Ap[fm * 16 * D];        // k-chunk lhi
        af1[fm] = *(const short8*)&Ap[fm * 16 * D + 32];   // k-chunk 4+lhi
    }
    f32x4 u4[4];                                           // exact C-in layout
    const float* uptr = nA + a0 + wm + lhi * 4;
#pragma unroll
    for (int fm = 0; fm < 4; ++fm) u4[fm] = *(const f32x4*)(uptr + fm * 16);

    const float* nBt = nB + (size_t)bj0 * TILE;
    float local = 0.f;

    // ---- helpers (all-static indexing after unroll) ----
    auto LOADB = [&](short8 (&bb)[8], float (&vcc)[4], int t) {
        const unsigned short* bp = Bbase + ((size_t)(bj0 + t) * TILE + wn + llo) * D + lhi * 8;
        const float* np = nBt + (size_t)t * TILE + wn + llo;
#pragma unroll
        for (int fn = 0; fn < 4; ++fn) {
            bb[fn]     = *(const short8*)&bp[fn * 16 * D];
            bb[4 + fn] = *(const short8*)&bp[fn * 16 * D + 32];
            vcc[fn]    = np[fn * 16];
        }
    };

    auto COMPUTE = [&](const short8 (&bb)[8], const float (&vcc)[4], int tt) {
        // acc = u4 (C-in) - 2C*dot after both k-steps => acc = C*n_i - 2C*dot
        f32x4 acc[4][4];
#pragma unroll
        for (int fm = 0; fm < 4; ++fm)
#pragma unroll
            for (int fn = 0; fn < 4; ++fn) {
                acc[fm][fn] = __builtin_amdgcn_mfma_f32_16x16x32_bf16(af0[fm], bb[fn],     u4[fm],      0, 0, 0);
                acc[fm][fn] = __builtin_amdgcn_mfma_f32_16x16x32_bf16(af1[fm], bb[4 + fn], acc[fm][fn], 0, 0, 0);
            }

        const bool diag = (z < 2) && (c == 0) && (tt == 0);   // bj==bi tile
        if (diag) {
            float ts = 0.f;
#pragma unroll
            for (int fm = 0; fm < 4; ++fm)
#pragma unroll
                for (int fn = 0; fn < 4; ++fn)
#pragma unroll
                    for (int rr = 0; rr < 4; ++rr) {
                        float term = __builtin_amdgcn_exp2f(fminf(acc[fm][fn][rr] + vcc[fn], 0.f));
                        int gm = wm + fm * 16 + lhi * 4 + rr;
                        int gn = wn + fn * 16 + llo;
                        if (gm == gn && a0 + gm < rA) term = 1.0f;
                        ts += term;
                    }
            local += ts;                       // diagonal tile, weight 1
        } else {
            // bound: max(acc) + max(v); triples -> v_max3 fusion
            float m[16];
#pragma unroll
            for (int fm = 0; fm < 4; ++fm)
#pragma unroll
                for (int fn = 0; fn < 4; ++fn) {
                    f32x4 a = acc[fm][fn];
                    m[fm * 4 + fn] = fmaxf(fmaxf(fmaxf(a[0], a[1]), a[2]), a[3]);
                }
            float q0 = fmaxf(fmaxf(m[0],  m[1]),  m[2]);
            float q1 = fmaxf(fmaxf(m[3],  m[4]),  m[5]);
            float q2 = fmaxf(fmaxf(m[6],  m[7]),  m[8]);
            float q3 = fmaxf(fmaxf(m[9],  m[10]), m[11]);
            float q4 = fmaxf(fmaxf(m[12], m[13]), m[14]);
            float mx = fmaxf(fmaxf(fmaxf(q0, q1), fmaxf(q2, q3)), fmaxf(q4, m[15]));
            float vmax = fmaxf(fmaxf(vcc[0], vcc[1]), fmaxf(vcc[2], vcc[3]));
            if (__any(mx + vmax > THR)) {
                float ts = 0.f;
#pragma unroll
                for (int fm = 0; fm < 4; ++fm)
#pragma unroll
                    for (int fn = 0; fn < 4; ++fn)
#pragma unroll
                        for (int rr = 0; rr < 4; ++rr)
                            ts += __builtin_amdgcn_exp2f(fminf(acc[fm][fn][rr] + vcc[fn], 0.f));
                if (z < 2) ts *= 2.f;          // symmetric off-diagonal
                local += ts;
            }
        }
    };

    // ---- main loop: unroll-2 ping-pong, one-tile-ahead register prefetch ----
    short8 bA[8], bB[8];
    float  vA[4], vB[4];
    LOADB(bA, vA, 0);
    for (int t = 0; ; t += 2) {
        if (t + 1 < ntiles) LOADB(bB, vB, t + 1);
        COMPUTE(bA, vA, t);
        if (t + 1 >= ntiles) break;
        if (t + 2 < ntiles) LOADB(bA, vA, t + 2);
        COMPUTE(bB, vB, t + 1);
        if (t + 2 >= ntiles) break;
    }

    // ---- wave reduction -> per-wave partial (no cross-wave sync at all) ----
#pragma unroll
    for (int mm = 32; mm > 0; mm >>= 1) local += __shfl_xor(local, mm, 64);
    if (lane == 0) part[lin4] = local;
}

// ---------------------------------------------------------------------------
// Final reduce over 3 x (NT*CH*4) per-wave partials (double), combine MMD.
// ---------------------------------------------------------------------------
__global__ void reduce_kernel(const float* __restrict__ part, float* __restrict__ out,
                              int seg, int nX, int nY) {
    __shared__ double sh[3][4];
    const int tid = threadIdx.x;
    double s0 = 0, s1 = 0, s2 = 0;
    for (int i = tid; i < seg; i += 256) {
        s0 += (double)part[i];
        s1 += (double)part[seg + i];
        s2 += (double)part[2 * seg + i];
    }
#pragma unroll
    for (int m = 32; m > 0; m >>= 1) {
        s0 += __shfl_xor(s0, m, 64);
        s1 += __shfl_xor(s1, m, 64);
        s2 += __shfl_xor(s2, m, 64);
    }
    const int w = tid >> 6, lane = tid & 63;
    if (lane == 0) { sh[0][w] = s0; sh[1][w] = s1; sh[2][w] = s2; }
    __syncthreads();
    if (tid == 0) {
        double xx = sh[0][0] + sh[0][1] + sh[0][2] + sh[0][3];
        double yy = sh[1][0] + sh[1][1] + sh[1][2] + sh[1][3];
        double xy = sh[2][0] + sh[2][1] + sh[2][2] + sh[2][3];
        out[0] = (float)(xx / ((double)nX * (double)nX)
                       + yy / ((double)nY * (double)nY)
                       - 2.0 * xy / ((double)nX * (double)nY));
    }
}

extern "C" void kernel_launch(void* const* d_in, const int* in_sizes, int n_in,
                              void* d_out, int out_size, void* d_ws, size_t ws_size,
                              hipStream_t stream) {
    const float* X = (const float*)d_in[0];
    const float* Y = (const float*)d_in[1];
    const int nX = in_sizes[0] / D;
    const int nY = in_sizes[1] / D;
    const int nMax = nX > nY ? nX : nY;
    const int NT   = (nMax + TILE - 1) / TILE;
    const int padN = NT * TILE;
    const int CH   = (NT + W - 1) / W;

    // ws layout (256B-aligned):
    //   part[3*NT*CH*4] f32 | nx[padN] f32 | ny[padN] f32 | Xbf[padN*64] bf16 | Ybf[padN*64] bf16
    char* ws = (char*)d_ws;
    size_t off = 0;
    float* part = (float*)(ws + off); off += ((size_t)3 * NT * CH * 4 * 4 + 255) & ~(size_t)255;
    float* nxp  = (float*)(ws + off); off += ((size_t)padN * 4 + 255) & ~(size_t)255;
    float* nyp  = (float*)(ws + off); off += ((size_t)padN * 4 + 255) & ~(size_t)255;
    unsigned short* Xbf = (unsigned short*)(ws + off); off += ((size_t)padN * D * 2 + 255) & ~(size_t)255;
    unsigned short* Ybf = (unsigned short*)(ws + off);

    int chunks = 2 * padN * 8;
    prep_kernel<<<(chunks + 255) / 256, 256, 0, stream>>>(X, Y, Xbf, Ybf, nxp, nyp, nX, nY, padN);

    dim3 grid(CH, NT, 3);
    gram_kernel<<<grid, 256, 0, stream>>>(Xbf, Ybf, nxp, nyp, nX, nY, NT, CH, part);

    reduce_kernel<<<1, 256, 0, stream>>>(part, (float*)d_out, NT * CH * 4, nX, nY);
}

// Round 7
// 135.385 us; speedup vs baseline: 1.7170x; 1.7170x over previous
//
#include <hip/hip_runtime.h>

#define D 64
#define TILE 128
#define W 16            // B-tiles per block (chunk length)

typedef __attribute__((ext_vector_type(8))) short short8;
typedef __attribute__((ext_vector_type(4))) float f32x4;
typedef __attribute__((ext_vector_type(8))) unsigned short ushort8;

#define CC     (-0.7213475204444817f)   // -log2(e)/(2*sigma^2), sigma=1
#define SCALE  (1.2011224087864498f)    // sqrt(2*log2(e)); dot(scaled) = -2C*dot
#define THR    (-28.0f)                 // drop terms < 2^-28: total mass < 3 -> <3e-8 on output

typedef const __attribute__((address_space(1))) void* gptr_t;
typedef __attribute__((address_space(3))) void* lptr_t;

// ---------------------------------------------------------------------------
// Prep: fp32 -> bf16 (RNE), PRE-SCALED by sqrt(2*log2 e), pre-swizzled within
// each 128B row (chunk' = chunk ^ (row&7), chunk = 8 bf16 = 16B) so that the
// linear global_load_lds staging + swizzled ds_read_b128 is bank-conflict-free.
// Norms stored PRE-MULTIPLIED by C. Padded rows: zeros + C*1e30.
// ---------------------------------------------------------------------------
__global__ void prep_kernel(const float* __restrict__ X, const float* __restrict__ Y,
                            unsigned short* __restrict__ Xbf, unsigned short* __restrict__ Ybf,
                            float* __restrict__ nx, float* __restrict__ ny,
                            int nX, int nY, int padN) {
    int t = blockIdx.x * blockDim.x + threadIdx.x;
    int half = padN * 8;
    if (t >= 2 * half) return;

    const float* src; unsigned short* dst; float* nrm; int n; int tt;
    if (t < half) { src = X; dst = Xbf; nrm = nx; n = nX; tt = t; }
    else          { src = Y; dst = Ybf; nrm = ny; n = nY; tt = t - half; }

    int row = tt >> 3, c8 = tt & 7;

    float v[8];
    float ss = 0.f;
    if (row < n) {
        const float4* p = (const float4*)(src + (size_t)row * D + c8 * 8);
        float4 f0 = p[0], f1 = p[1];
        v[0] = f0.x; v[1] = f0.y; v[2] = f0.z; v[3] = f0.w;
        v[4] = f1.x; v[5] = f1.y; v[6] = f1.z; v[7] = f1.w;
#pragma unroll
        for (int i = 0; i < 8; ++i) ss += v[i] * v[i];
    } else {
#pragma unroll
        for (int i = 0; i < 8; ++i) v[i] = 0.f;
    }

    ss += __shfl_xor(ss, 1, 64);
    ss += __shfl_xor(ss, 2, 64);
    ss += __shfl_xor(ss, 4, 64);

    ushort8 o;
#pragma unroll
    for (int i = 0; i < 8; ++i) {
        unsigned u = __float_as_uint(v[i] * SCALE);
        o[i] = (unsigned short)((u + 0x7fffu + ((u >> 16) & 1u)) >> 16);   // RNE
    }
    *(ushort8*)(dst + (size_t)row * D + ((c8 ^ (row & 7)) << 3)) = o;

    if (c8 == 0) nrm[row] = (row < n) ? (CC * ss) : (CC * 1e30f);
}

// ---------------------------------------------------------------------------
// Barrier-FREE persistent-A gram kernel with wave-private LDS staging.
// Each wave owns a 64x64 sub-tile: A-frags + A-norms (u4 = MFMA C-in) in
// registers for the whole block; its B-half (8KB) + B-norms (256B) staged by
// ITSELF into its own double-buffered LDS region via global_load_lds ->
// producer == consumer == same wave -> ordering by counted vmcnt(9) only,
// no s_barrier / __syncthreads anywhere. Waves free-run: one wave's MFMA
// overlaps another's epilogue VALU on the same SIMD; setprio(1) biases the
// MFMA cluster (waves are phase-diverse, so it has something to arbitrate).
// Fast path: bound = max(acc)+max(v) vs THR, one __any branch.
// z=0: xx (bj>=bi, x2 off-diag), z=1: yy, z=2: xy (full rows).
// ---------------------------------------------------------------------------
__launch_bounds__(256, 2)
__global__ void gram_kernel(const unsigned short* __restrict__ Xbf,
                            const unsigned short* __restrict__ Ybf,
                            const float* __restrict__ nx, const float* __restrict__ ny,
                            int nX, int nY, int NT, int CH, float* __restrict__ part) {
    __shared__ char lds[4][2][8448];   // [wave][parity][8KB B-frags + 256B norms]

    const int c   = blockIdx.x;
    const int bi  = blockIdx.y;
    const int z   = blockIdx.z;
    const int tid = threadIdx.x;
    const int w = tid >> 6, lane = tid & 63;
    const int lin4 = ((z * NT + bi) * CH + c) * 4 + w;

    const int bj0 = (z < 2 ? bi : 0) + c * W;
    int ntiles = NT - bj0; if (ntiles > W) ntiles = W;
    if (ntiles <= 0) { if (lane == 0) part[lin4] = 0.f; return; }

    const unsigned short* Abase; const unsigned short* Bbase;
    const float* nA; const float* nB; int rA;
    if (z == 0)      { Abase = Xbf; Bbase = Xbf; nA = nx; nB = nx; rA = nX; }
    else if (z == 1) { Abase = Ybf; Bbase = Ybf; nA = ny; nB = ny; rA = nY; }
    else             { Abase = Xbf; Bbase = Ybf; nA = nx; nB = ny; rA = nX; }

    const int a0 = bi * TILE;
    const int wm = (w & 1) * 64, wn = (w >> 1) * 64;
    const int lhi = lane >> 4, llo = lane & 15;
    const int sw = llo & 7;

    char* buf0 = &lds[w][0][0];
    char* buf1 = &lds[w][1][0];

    // ---- stage tile t's B-half + norms into dst (9 global_load_lds) ----
    const char*  Bby = (const char*)Bbase;
    const float* nBt = nB;
    auto STAGE = [&](int t, char* dst) {
        const char* src = Bby + (((size_t)(bj0 + t) * TILE + wn) * D) * 2;
#pragma unroll
        for (int i = 0; i < 8; ++i)
            __builtin_amdgcn_global_load_lds(
                (gptr_t)(src + i * 1024 + lane * 16),
                (lptr_t)(dst + i * 1024), 16, 0, 0);
        if (lane < 16)
            __builtin_amdgcn_global_load_lds(
                (gptr_t)((const char*)(nBt + (size_t)(bj0 + t) * TILE + wn) + lane * 16),
                (lptr_t)(dst + 8192), 16, 0, 0);
    };

    // ---- prologue: stage tile 0; A-frags + A-norms to regs (L2-hot) ----
    STAGE(0, buf0);

    const unsigned short* Ab = Abase + (size_t)(a0 + wm) * D;
    short8 af0[4], af1[4];
#pragma unroll
    for (int fm = 0; fm < 4; ++fm) {
        int r = fm * 16 + llo;
        af0[fm] = *(const short8*)&Ab[r * D + ((lhi       ^ sw) << 3)];
        af1[fm] = *(const short8*)&Ab[r * D + (((4 + lhi) ^ sw) << 3)];
    }
    f32x4 u4[4];                                           // exact C-in layout
    const float* uptr = nA + a0 + wm + lhi * 4;
#pragma unroll
    for (int fm = 0; fm < 4; ++fm) u4[fm] = *(const f32x4*)(uptr + fm * 16);

    const int bb0 = ((lhi     ^ sw) << 4);   // byte offset in row, ks=0
    const int bb1 = (((4+lhi) ^ sw) << 4);   // ks=1

    float local = 0.f;

    // ---- main loop: wave-private double buffer, counted vmcnt, no barriers ----
    for (int t = 0; t < ntiles; ++t) {
        char* bcur = (t & 1) ? buf1 : buf0;

        if (t + 1 < ntiles) {
            STAGE(t + 1, (t & 1) ? buf0 : buf1);
            // the 9 loads just issued stay in flight; tile t's 9 are drained
            asm volatile("s_waitcnt vmcnt(9)" ::: "memory");
        } else {
            asm volatile("s_waitcnt vmcnt(0)" ::: "memory");
        }

        // B fragments + norms from OWN staged LDS (swizzled rows: 2-way max)
        short8 bf0[4], bf1[4];
        float vc[4];
#pragma unroll
        for (int fn = 0; fn < 4; ++fn) {
            const char* rp = bcur + (fn * 16 + llo) * 128;
            bf0[fn] = *(const short8*)(rp + bb0);
            bf1[fn] = *(const short8*)(rp + bb1);
            vc[fn]  = *(const float*)(bcur + 8192 + (fn * 16 + llo) * 4);
        }

        // acc = u4 (C-in) + dot-part; after both k-steps: acc = C*n_i - 2C*dot
        f32x4 acc[4][4];
        __builtin_amdgcn_s_setprio(1);
#pragma unroll
        for (int fm = 0; fm < 4; ++fm)
#pragma unroll
            for (int fn = 0; fn < 4; ++fn) {
                acc[fm][fn] = __builtin_amdgcn_mfma_f32_16x16x32_bf16(af0[fm], bf0[fn], u4[fm],      0, 0, 0);
                acc[fm][fn] = __builtin_amdgcn_mfma_f32_16x16x32_bf16(af1[fm], bf1[fn], acc[fm][fn], 0, 0, 0);
            }
        __builtin_amdgcn_s_setprio(0);

        // ---- epilogue ----
        const bool diag = (z < 2) && (c == 0) && (t == 0);   // bj==bi tile
        if (diag) {
            float ts = 0.f;
#pragma unroll
            for (int fm = 0; fm < 4; ++fm)
#pragma unroll
                for (int fn = 0; fn < 4; ++fn)
#pragma unroll
                    for (int rr = 0; rr < 4; ++rr) {
                        float term = __builtin_amdgcn_exp2f(fminf(acc[fm][fn][rr] + vc[fn], 0.f));
                        int gm = wm + fm * 16 + lhi * 4 + rr;
                        int gn = wn + fn * 16 + llo;
                        if (gm == gn && a0 + gm < rA) term = 1.0f;
                        ts += term;
                    }
            local += ts;                       // diagonal tile, weight 1
        } else {
            // bound: max(acc) + max(v); triples -> v_max3 fusion
            float m[16];
#pragma unroll
            for (int fm = 0; fm < 4; ++fm)
#pragma unroll
                for (int fn = 0; fn < 4; ++fn) {
                    f32x4 a = acc[fm][fn];
                    m[fm * 4 + fn] = fmaxf(fmaxf(fmaxf(a[0], a[1]), a[2]), a[3]);
                }
            float q0 = fmaxf(fmaxf(m[0],  m[1]),  m[2]);
            float q1 = fmaxf(fmaxf(m[3],  m[4]),  m[5]);
            float q2 = fmaxf(fmaxf(m[6],  m[7]),  m[8]);
            float q3 = fmaxf(fmaxf(m[9],  m[10]), m[11]);
            float q4 = fmaxf(fmaxf(m[12], m[13]), m[14]);
            float mx = fmaxf(fmaxf(fmaxf(q0, q1), fmaxf(q2, q3)), fmaxf(q4, m[15]));
            float vmax = fmaxf(fmaxf(vc[0], vc[1]), fmaxf(vc[2], vc[3]));
            if (__any(mx + vmax > THR)) {
                float ts = 0.f;
#pragma unroll
                for (int fm = 0; fm < 4; ++fm)
#pragma unroll
                    for (int fn = 0; fn < 4; ++fn)
#pragma unroll
                        for (int rr = 0; rr < 4; ++rr)
                            ts += __builtin_amdgcn_exp2f(fminf(acc[fm][fn][rr] + vc[fn], 0.f));
                if (z < 2) ts *= 2.f;          // symmetric off-diagonal
                local += ts;
            }
        }
    }

    // ---- wave reduction -> per-wave partial (no cross-wave sync at all) ----
#pragma unroll
    for (int mm = 32; mm > 0; mm >>= 1) local += __shfl_xor(local, mm, 64);
    if (lane == 0) part[lin4] = local;
}

// ---------------------------------------------------------------------------
// Final reduce over 3 x (NT*CH*4) per-wave partials (double), combine MMD.
// ---------------------------------------------------------------------------
__global__ void reduce_kernel(const float* __restrict__ part, float* __restrict__ out,
                              int seg, int nX, int nY) {
    __shared__ double sh[3][4];
    const int tid = threadIdx.x;
    double s0 = 0, s1 = 0, s2 = 0;
    for (int i = tid; i < seg; i += 256) {
        s0 += (double)part[i];
        s1 += (double)part[seg + i];
        s2 += (double)part[2 * seg + i];
    }
#pragma unroll
    for (int m = 32; m > 0; m >>= 1) {
        s0 += __shfl_xor(s0, m, 64);
        s1 += __shfl_xor(s1, m, 64);
        s2 += __shfl_xor(s2, m, 64);
    }
    const int w = tid >> 6, lane = tid & 63;
    if (lane == 0) { sh[0][w] = s0; sh[1][w] = s1; sh[2][w] = s2; }
    __syncthreads();
    if (tid == 0) {
        double xx = sh[0][0] + sh[0][1] + sh[0][2] + sh[0][3];
        double yy = sh[1][0] + sh[1][1] + sh[1][2] + sh[1][3];
        double xy = sh[2][0] + sh[2][1] + sh[2][2] + sh[2][3];
        out[0] = (float)(xx / ((double)nX * (double)nX)
                       + yy / ((double)nY * (double)nY)
                       - 2.0 * xy / ((double)nX * (double)nY));
    }
}

extern "C" void kernel_launch(void* const* d_in, const int* in_sizes, int n_in,
                              void* d_out, int out_size, void* d_ws, size_t ws_size,
                              hipStream_t stream) {
    const float* X = (const float*)d_in[0];
    const float* Y = (const float*)d_in[1];
    const int nX = in_sizes[0] / D;
    const int nY = in_sizes[1] / D;
    const int nMax = nX > nY ? nX : nY;
    const int NT   = (nMax + TILE - 1) / TILE;
    const int padN = NT * TILE;
    const int CH   = (NT + W - 1) / W;

    // ws layout (256B-aligned):
    //   part[3*NT*CH*4] f32 | nx[padN] f32 | ny[padN] f32 | Xbf[padN*64] bf16 | Ybf[padN*64] bf16
    char* ws = (char*)d_ws;
    size_t off = 0;
    float* part = (float*)(ws + off); off += ((size_t)3 * NT * CH * 4 * 4 + 255) & ~(size_t)255;
    float* nxp  = (float*)(ws + off); off += ((size_t)padN * 4 + 255) & ~(size_t)255;
    float* nyp  = (float*)(ws + off); off += ((size_t)padN * 4 + 255) & ~(size_t)255;
    unsigned short* Xbf = (unsigned short*)(ws + off); off += ((size_t)padN * D * 2 + 255) & ~(size_t)255;
    unsigned short* Ybf = (unsigned short*)(ws + off);

    int chunks = 2 * padN * 8;
    prep_kernel<<<(chunks + 255) / 256, 256, 0, stream>>>(X, Y, Xbf, Ybf, nxp, nyp, nX, nY, padN);

    dim3 grid(CH, NT, 3);
    gram_kernel<<<grid, 256, 0, stream>>>(Xbf, Ybf, nxp, nyp, nX, nY, NT, CH, part);

    reduce_kernel<<<1, 256, 0, stream>>>(part, (float*)d_out, NT * CH * 4, nX, nY);
}

// Round 8
// 122.686 us; speedup vs baseline: 1.8948x; 1.1035x over previous
//
#include <hip/hip_runtime.h>

#define D 64
#define TILE 128
#define W 8             // B-tiles per block (chunk length)

typedef __attribute__((ext_vector_type(8))) short short8;
typedef __attribute__((ext_vector_type(4))) float f32x4;
typedef __attribute__((ext_vector_type(8))) unsigned short ushort8;

#define CC     (-0.7213475204444817f)   // -log2(e)/(2*sigma^2), sigma=1
#define SCALE  (1.2011224087864498f)    // sqrt(2*log2(e)); dot(scaled) = -2C*dot
#define THR    (-28.0f)                 // drop terms < 2^-28: total mass < 3 -> <3e-8 on output

typedef const __attribute__((address_space(1))) void* gptr_t;
typedef __attribute__((address_space(3))) void* lptr_t;

// ---------------------------------------------------------------------------
// Prep: fp32 -> bf16 (RNE), PRE-SCALED by sqrt(2*log2 e), pre-swizzled within
// each 128B row (chunk' = chunk ^ (row&7), chunk = 8 bf16 = 16B) so linear
// global_load_lds staging + swizzled ds_read_b128 is bank-conflict-free.
// Norms stored PRE-MULTIPLIED by C. Padded rows: zeros + C*1e30.
// ---------------------------------------------------------------------------
__global__ void prep_kernel(const float* __restrict__ X, const float* __restrict__ Y,
                            unsigned short* __restrict__ Xbf, unsigned short* __restrict__ Ybf,
                            float* __restrict__ nx, float* __restrict__ ny,
                            int nX, int nY, int padN) {
    int t = blockIdx.x * blockDim.x + threadIdx.x;
    int half = padN * 8;
    if (t >= 2 * half) return;

    const float* src; unsigned short* dst; float* nrm; int n; int tt;
    if (t < half) { src = X; dst = Xbf; nrm = nx; n = nX; tt = t; }
    else          { src = Y; dst = Ybf; nrm = ny; n = nY; tt = t - half; }

    int row = tt >> 3, c8 = tt & 7;

    float v[8];
    float ss = 0.f;
    if (row < n) {
        const float4* p = (const float4*)(src + (size_t)row * D + c8 * 8);
        float4 f0 = p[0], f1 = p[1];
        v[0] = f0.x; v[1] = f0.y; v[2] = f0.z; v[3] = f0.w;
        v[4] = f1.x; v[5] = f1.y; v[6] = f1.z; v[7] = f1.w;
#pragma unroll
        for (int i = 0; i < 8; ++i) ss += v[i] * v[i];
    } else {
#pragma unroll
        for (int i = 0; i < 8; ++i) v[i] = 0.f;
    }

    ss += __shfl_xor(ss, 1, 64);
    ss += __shfl_xor(ss, 2, 64);
    ss += __shfl_xor(ss, 4, 64);

    ushort8 o;
#pragma unroll
    for (int i = 0; i < 8; ++i) {
        unsigned u = __float_as_uint(v[i] * SCALE);
        o[i] = (unsigned short)((u + 0x7fffu + ((u >> 16) & 1u)) >> 16);   // RNE
    }
    *(ushort8*)(dst + (size_t)row * D + ((c8 ^ (row & 7)) << 3)) = o;

    if (c8 == 0) nrm[row] = (row < n) ? (CC * ss) : (CC * 1e30f);
}

// ---------------------------------------------------------------------------
// Persistent-A gram kernel, 4 blocks/CU. Shared double-buffered B staging
// (counted vmcnt(5), 2 barriers/tile); A-frags + A-norms (u4 = MFMA C-in) in
// registers for the whole block. Per-tile compute is folded PER fm-ROW:
// 8 MFMAs -> 16 acc values -> max-bound/epilogue -> acc released. This keeps
// live acc at 16 regs so the kernel fits 128 VGPR = 4 blocks/CU; cross-block
// phase diversity fills the matrix pipe during other blocks' epilogues.
// z=0: xx (bj>=bi, x2 off-diag), z=1: yy, z=2: xy (full rows).
// ---------------------------------------------------------------------------
__launch_bounds__(256, 4)
__global__ void gram_kernel(const unsigned short* __restrict__ Xbf,
                            const unsigned short* __restrict__ Ybf,
                            const float* __restrict__ nx, const float* __restrict__ ny,
                            int nX, int nY, int NT, int CH, float* __restrict__ part) {
    __shared__ unsigned short Bbuf[2][TILE * D];   // 2 x 16KB
    __shared__ float Bnorm[2][TILE];               // 2 x 512B
    __shared__ float red[4];

    const int c   = blockIdx.x;
    const int bi  = blockIdx.y;
    const int z   = blockIdx.z;
    const int tid = threadIdx.x;
    const int lin = (z * NT + bi) * CH + c;

    const int bj0 = (z < 2 ? bi : 0) + c * W;
    int ntiles = NT - bj0; if (ntiles > W) ntiles = W;
    if (ntiles <= 0) { if (tid == 0) part[lin] = 0.f; return; }

    const unsigned short* Abase; const unsigned short* Bbase;
    const float* nA; const float* nB; int rA;
    if (z == 0)      { Abase = Xbf; Bbase = Xbf; nA = nx; nB = nx; rA = nX; }
    else if (z == 1) { Abase = Ybf; Bbase = Ybf; nA = ny; nB = ny; rA = nY; }
    else             { Abase = Xbf; Bbase = Ybf; nA = nx; nB = ny; rA = nX; }

    const int a0 = bi * TILE;
    const int w = tid >> 6, lane = tid & 63;
    const int wm = (w & 1) * 64, wn = (w >> 1) * 64;
    const int lhi = lane >> 4, llo = lane & 15;
    const int sw = llo & 7;

    // ---- cooperative stage of one 16KB B-tile + 512B norms ----
    const char*  Bsrc = (const char*)(Bbase + (size_t)bj0 * TILE * D);   // +16KB/tile
    const float* nBt  = nB + (size_t)bj0 * TILE;
    auto STAGE = [&](int t, int par) {
        const char* src = Bsrc + (size_t)t * TILE * D * 2;
#pragma unroll
        for (int cIdx = 0; cIdx < 4; ++cIdx) {
            int off = w * 4096 + cIdx * 1024;
            __builtin_amdgcn_global_load_lds((gptr_t)(src + off + lane * 16),
                                             (lptr_t)((char*)&Bbuf[par][0] + off), 16, 0, 0);
        }
        if (lane < 8)
            __builtin_amdgcn_global_load_lds(
                (gptr_t)((const char*)(nBt + (size_t)t * TILE + w * 32) + lane * 16),
                (lptr_t)(&Bnorm[par][w * 32]), 16, 0, 0);
    };

    // ---- prologue: stage tile 0; A-frags + A-norms into registers ----
    STAGE(0, 0);

    const unsigned short* Ab = Abase + (size_t)(a0 + wm) * D;
    short8 af0[4], af1[4];
#pragma unroll
    for (int fm = 0; fm < 4; ++fm) {
        int r = fm * 16 + llo;
        af0[fm] = *(const short8*)&Ab[r * D + ((lhi       ^ sw) << 3)];
        af1[fm] = *(const short8*)&Ab[r * D + (((4 + lhi) ^ sw) << 3)];
    }
    f32x4 u4[4];                                           // exact C-in layout
    const float* uptr = nA + a0 + wm + lhi * 4;
#pragma unroll
    for (int fm = 0; fm < 4; ++fm) u4[fm] = *(const f32x4*)(uptr + fm * 16);

    const int bb0 = (lhi       ^ sw) << 3;    // element offset in row, ks=0
    const int bb1 = ((4 + lhi) ^ sw) << 3;    // ks=1

    float local = 0.f;

    // ---- main loop over B-tiles ----
    for (int t = 0; t < ntiles; ++t) {
        const int cur = t & 1;

        if (t + 1 < ntiles) {
            STAGE(t + 1, cur ^ 1);
            asm volatile("s_waitcnt vmcnt(5)" ::: "memory");   // tile t's 5 drained
        } else {
            asm volatile("s_waitcnt vmcnt(0)" ::: "memory");
        }
        __builtin_amdgcn_s_barrier();          // B1: Bbuf[cur]/Bnorm[cur] ready

        // B fragments + norms from LDS (swizzled rows -> conflict-free)
        short8 bf0[4], bf1[4];
        float vc[4];
#pragma unroll
        for (int fn = 0; fn < 4; ++fn) {
            int r = (wn + fn * 16 + llo) * D;
            bf0[fn] = *(const short8*)&Bbuf[cur][r + bb0];
            bf1[fn] = *(const short8*)&Bbuf[cur][r + bb1];
            vc[fn]  = Bnorm[cur][wn + fn * 16 + llo];
        }
        const float vmax = fmaxf(fmaxf(vc[0], vc[1]), fmaxf(vc[2], vc[3]));
        const bool diag = (z < 2) && (c == 0) && (t == 0);   // bj==bi tile

        // ---- per-fm fold: 8 MFMAs -> bound/epilogue -> release acc ----
#pragma unroll
        for (int fm = 0; fm < 4; ++fm) {
            f32x4 acc[4];
            __builtin_amdgcn_s_setprio(1);
#pragma unroll
            for (int fn = 0; fn < 4; ++fn) {
                acc[fn] = __builtin_amdgcn_mfma_f32_16x16x32_bf16(af0[fm], bf0[fn], u4[fm], 0, 0, 0);
                acc[fn] = __builtin_amdgcn_mfma_f32_16x16x32_bf16(af1[fm], bf1[fn], acc[fn], 0, 0, 0);
            }
            __builtin_amdgcn_s_setprio(0);

            if (diag) {
                float ts = 0.f;
#pragma unroll
                for (int fn = 0; fn < 4; ++fn)
#pragma unroll
                    for (int rr = 0; rr < 4; ++rr) {
                        float term = __builtin_amdgcn_exp2f(fminf(acc[fn][rr] + vc[fn], 0.f));
                        int gm = wm + fm * 16 + lhi * 4 + rr;
                        int gn = wn + fn * 16 + llo;
                        if (gm == gn && a0 + gm < rA) term = 1.0f;
                        ts += term;
                    }
                local += ts;                   // diagonal tile, weight 1
            } else {
                float m0 = fmaxf(fmaxf(acc[0][0], acc[0][1]), fmaxf(acc[0][2], acc[0][3]));
                float m1 = fmaxf(fmaxf(acc[1][0], acc[1][1]), fmaxf(acc[1][2], acc[1][3]));
                float m2 = fmaxf(fmaxf(acc[2][0], acc[2][1]), fmaxf(acc[2][2], acc[2][3]));
                float m3 = fmaxf(fmaxf(acc[3][0], acc[3][1]), fmaxf(acc[3][2], acc[3][3]));
                float mx = fmaxf(fmaxf(m0, m1), fmaxf(m2, m3));
                if (__any(mx + vmax > THR)) {
                    float ts = 0.f;
#pragma unroll
                    for (int fn = 0; fn < 4; ++fn)
#pragma unroll
                        for (int rr = 0; rr < 4; ++rr)
                            ts += __builtin_amdgcn_exp2f(fminf(acc[fn][rr] + vc[fn], 0.f));
                    if (z < 2) ts *= 2.f;      // symmetric off-diagonal
                    local += ts;
                }
            }
        }

        asm volatile("s_waitcnt lgkmcnt(0)" ::: "memory");
        __builtin_amdgcn_s_barrier();          // B2: Bbuf[cur] free for overwrite
    }

    // ---- block reduction -> per-block partial ----
#pragma unroll
    for (int mm = 32; mm > 0; mm >>= 1) local += __shfl_xor(local, mm, 64);
    if (lane == 0) red[w] = local;
    __syncthreads();
    if (tid == 0) part[lin] = red[0] + red[1] + red[2] + red[3];
}

// ---------------------------------------------------------------------------
// Final reduce over 3 x NT x CH partials (double), combine MMD.
// ---------------------------------------------------------------------------
__global__ void reduce_kernel(const float* __restrict__ part, float* __restrict__ out,
                              int seg, int nX, int nY) {
    __shared__ double sh[3][4];
    const int tid = threadIdx.x;
    double s0 = 0, s1 = 0, s2 = 0;
    for (int i = tid; i < seg; i += 256) {
        s0 += (double)part[i];
        s1 += (double)part[seg + i];
        s2 += (double)part[2 * seg + i];
    }
#pragma unroll
    for (int m = 32; m > 0; m >>= 1) {
        s0 += __shfl_xor(s0, m, 64);
        s1 += __shfl_xor(s1, m, 64);
        s2 += __shfl_xor(s2, m, 64);
    }
    const int w = tid >> 6, lane = tid & 63;
    if (lane == 0) { sh[0][w] = s0; sh[1][w] = s1; sh[2][w] = s2; }
    __syncthreads();
    if (tid == 0) {
        double xx = sh[0][0] + sh[0][1] + sh[0][2] + sh[0][3];
        double yy = sh[1][0] + sh[1][1] + sh[1][2] + sh[1][3];
        double xy = sh[2][0] + sh[2][1] + sh[2][2] + sh[2][3];
        out[0] = (float)(xx / ((double)nX * (double)nX)
                       + yy / ((double)nY * (double)nY)
                       - 2.0 * xy / ((double)nX * (double)nY));
    }
}

extern "C" void kernel_launch(void* const* d_in, const int* in_sizes, int n_in,
                              void* d_out, int out_size, void* d_ws, size_t ws_size,
                              hipStream_t stream) {
    const float* X = (const float*)d_in[0];
    const float* Y = (const float*)d_in[1];
    const int nX = in_sizes[0] / D;
    const int nY = in_sizes[1] / D;
    const int nMax = nX > nY ? nX : nY;
    const int NT   = (nMax + TILE - 1) / TILE;
    const int padN = NT * TILE;
    const int CH   = (NT + W - 1) / W;

    // ws layout (256B-aligned):
    //   part[3*NT*CH] f32 | nx[padN] f32 | ny[padN] f32 | Xbf[padN*64] bf16 | Ybf[padN*64] bf16
    char* ws = (char*)d_ws;
    size_t off = 0;
    float* part = (float*)(ws + off); off += ((size_t)3 * NT * CH * 4 + 255) & ~(size_t)255;
    float* nxp  = (float*)(ws + off); off += ((size_t)padN * 4 + 255) & ~(size_t)255;
    float* nyp  = (float*)(ws + off); off += ((size_t)padN * 4 + 255) & ~(size_t)255;
    unsigned short* Xbf = (unsigned short*)(ws + off); off += ((size_t)padN * D * 2 + 255) & ~(size_t)255;
    unsigned short* Ybf = (unsigned short*)(ws + off);

    int chunks = 2 * padN * 8;
    prep_kernel<<<(chunks + 255) / 256, 256, 0, stream>>>(X, Y, Xbf, Ybf, nxp, nyp, nX, nY, padN);

    dim3 grid(CH, NT, 3);
    gram_kernel<<<grid, 256, 0, stream>>>(Xbf, Ybf, nxp, nyp, nX, nY, NT, CH, part);

    reduce_kernel<<<1, 256, 0, stream>>>(part, (float*)d_out, NT * CH, nX, nY);
}